// Round 4
// baseline (384.656 us; speedup 1.0000x reference)
//
#include <hip/hip_runtime.h>

#define Bx 8
#define Tx 2048
#define Dx 1024
#define Hx 16
#define DHx 64
#define TSx 2047      // T-1 steps in the decayed sum
#define CLEN 512      // time-chunk length (4 chunks; last = 511)
#define TILE1 32      // staged steps per LDS tile in k_partial

// ---------------- kernel 1: per-(b,h,chunk) partial state ----------------
// partial_c[j,k] = sum_{i in chunk} k_i[j] * v_i[k] * prod_{m=i+1..chunk_end-1} w_m[k]
// prod_c[k]     = prod_{i in chunk} w_i[k]
__global__ __launch_bounds__(256, 2) void k_partial(
    const float* __restrict__ gw, const float* __restrict__ gk,
    const float* __restrict__ gv, float* __restrict__ part,
    float* __restrict__ prod) {
  __shared__ float sk[TILE1 * 64], sv[TILE1 * 64], sw[TILE1 * 64];
  const int bid = blockIdx.x;
  const int pair = bid >> 2, c = bid & 3;
  const int b = pair >> 4, h = pair & 15;
  const int c0 = c * CLEN;
  const int c1 = (c == 3) ? TSx : (c0 + CLEN);
  const int tid = threadIdx.x;
  const int kq = tid & 63;       // owned v-channel
  const int jb = tid >> 6;       // j block (16 j's) == wave id
  const size_t hb = (size_t)b * Tx * Dx + (size_t)h * DHx;
  const int lrow0 = tid >> 4;    // staging row within 16-row pass
  const int lcol = (tid & 15) * 4;

  float acc[16];
#pragma unroll
  for (int i = 0; i < 16; ++i) acc[i] = 0.f;
  float p = 1.f;

  float4 rk[2], rv[2], rw[2];

  int hi = c1;
  int lo = (hi - TILE1 > c0) ? (hi - TILE1) : c0;

  // prologue: first (highest-time) tile is always full 32 rows
#pragma unroll
  for (int ps = 0; ps < 2; ++ps) {
    const size_t off = hb + (size_t)(lo + ps * 16 + lrow0) * Dx + lcol;
    rk[ps] = *(const float4*)(gk + off);
    rv[ps] = *(const float4*)(gv + off);
    rw[ps] = *(const float4*)(gw + off);
  }
#pragma unroll
  for (int ps = 0; ps < 2; ++ps) {
    const int o = (ps * 16 + lrow0) * 64 + lcol;
    *(float4*)(sk + o) = rk[ps];
    *(float4*)(sv + o) = rv[ps];
    *(float4*)(sw + o) = rw[ps];
  }

  for (;;) {
    __syncthreads();                       // staged tile visible
    const int nrows = hi - lo;
    const bool more = (lo > c0);
    int nhi = lo, nlo = lo;
    if (more) {                            // T14: issue next-tile loads now
      nlo = (nhi - TILE1 > c0) ? (nhi - TILE1) : c0;
      const int nn = nhi - nlo;
#pragma unroll
      for (int ps = 0; ps < 2; ++ps) {
        const int row = ps * 16 + lrow0;
        if (row < nn) {
          const size_t off = hb + (size_t)(nlo + row) * Dx + lcol;
          rk[ps] = *(const float4*)(gk + off);
          rv[ps] = *(const float4*)(gv + off);
          rw[ps] = *(const float4*)(gw + off);
        }
      }
    }
    // backward scan over staged steps (descending time)
#pragma unroll 4
    for (int s = nrows - 1; s >= 0; --s) {
      const float vv = sv[s * 64 + kq];
      const float ww = sw[s * 64 + kq];
      const float wv = p * vv;             // Wdec(i) * v_i  (p = suffix prod, excl. i)
      p *= ww;                             // extend suffix to include i
      const float4* kp = (const float4*)(sk + s * 64 + jb * 16);  // broadcast
      const float4 k0 = kp[0], k1 = kp[1], k2 = kp[2], k3 = kp[3];
      acc[0]  = fmaf(k0.x, wv, acc[0]);
      acc[1]  = fmaf(k0.y, wv, acc[1]);
      acc[2]  = fmaf(k0.z, wv, acc[2]);
      acc[3]  = fmaf(k0.w, wv, acc[3]);
      acc[4]  = fmaf(k1.x, wv, acc[4]);
      acc[5]  = fmaf(k1.y, wv, acc[5]);
      acc[6]  = fmaf(k1.z, wv, acc[6]);
      acc[7]  = fmaf(k1.w, wv, acc[7]);
      acc[8]  = fmaf(k2.x, wv, acc[8]);
      acc[9]  = fmaf(k2.y, wv, acc[9]);
      acc[10] = fmaf(k2.z, wv, acc[10]);
      acc[11] = fmaf(k2.w, wv, acc[11]);
      acc[12] = fmaf(k3.x, wv, acc[12]);
      acc[13] = fmaf(k3.y, wv, acc[13]);
      acc[14] = fmaf(k3.z, wv, acc[14]);
      acc[15] = fmaf(k3.w, wv, acc[15]);
    }
    if (!more) break;
    __syncthreads();                       // everyone done reading LDS
    const int nn = nhi - nlo;
#pragma unroll
    for (int ps = 0; ps < 2; ++ps) {
      const int row = ps * 16 + lrow0;
      if (row < nn) {
        const int o = row * 64 + lcol;
        *(float4*)(sk + o) = rk[ps];
        *(float4*)(sv + o) = rv[ps];
        *(float4*)(sw + o) = rw[ps];
      }
    }
    hi = nhi; lo = nlo;
  }

  float* pb = part + (size_t)bid * 4096;
#pragma unroll
  for (int jj = 0; jj < 16; ++jj)
    pb[(jb * 16 + jj) * 64 + kq] = acc[jj];
  if (jb == 0) prod[bid * 64 + kq] = p;
}

// ---------------- kernel 2: combine chunks + u-term ----------------
__global__ __launch_bounds__(256) void k_combine(
    const float* __restrict__ part, const float* __restrict__ prod,
    const float* __restrict__ gk, const float* __restrict__ gv,
    const float* __restrict__ gu, float* __restrict__ wkv) {
  const int pair = blockIdx.x;
  const int b = pair >> 4, h = pair & 15;
  const int tid = threadIdx.x;
  const int kq = tid & 63, jb = tid >> 6;
  const size_t last = ((size_t)b * Tx + (Tx - 1)) * Dx + (size_t)h * DHx;
  const float p1 = prod[(pair * 4 + 1) * 64 + kq];
  const float p2 = prod[(pair * 4 + 2) * 64 + kq];
  const float p3 = prod[(pair * 4 + 3) * 64 + kq];
  const float s2 = p3, s1 = p3 * p2, s0 = p3 * p2 * p1;
  const float uv = gu[h * DHx + kq] * gv[last + kq];
  const float* pp = part + (size_t)(pair * 4) * 4096;
  float* wb = wkv + (size_t)pair * 4096;
#pragma unroll
  for (int jj = 0; jj < 16; ++jj) {
    const int j = jb * 16 + jj;
    const int o = j * 64 + kq;
    float r = pp[o] * s0 + pp[4096 + o] * s1 + pp[2 * 4096 + o] * s2 + pp[3 * 4096 + o];
    r = fmaf(gk[last + j], uv, r);
    wb[o] = r;
  }
}

// ---------------- kernel 3: out = r @ wkv, LN, silu(g) ----------------
#define LDP 68  // padded LDS row stride (floats); 68*4B keeps 16B alignment, breaks bank aliasing
__global__ __launch_bounds__(256, 4) void k_out(
    const float* __restrict__ gr, const float* __restrict__ gg,
    const float* __restrict__ wkv, const float* __restrict__ gamma,
    const float* __restrict__ beta, float* __restrict__ gout) {
  __shared__ float sW[64 * LDP];
  __shared__ float sR[64 * LDP];
  const int bid = blockIdx.x;
  const int pair = bid >> 3, tch = bid & 7;
  const int b = pair >> 4, h = pair & 15;
  const int tid = threadIdx.x;
  const int ki = tid & 15;      // k block (4 k's)
  const int ti = tid >> 4;      // t block (4 t's), 0..15
  const size_t hb = (size_t)b * Tx * Dx + (size_t)h * DHx;
  const int t0 = tch * 256;
  const int lcol = ki * 4;

  {  // stage wkv[64][64] -> padded LDS
    const float* wsrc = wkv + (size_t)pair * 4096;
    const int j = tid >> 2;
    const int cc = (tid & 3) * 16;
#pragma unroll
    for (int q = 0; q < 4; ++q) {
      const float4 x = *(const float4*)(wsrc + j * 64 + cc + q * 4);
      *(float4*)(sW + j * LDP + cc + q * 4) = x;
    }
  }
  float gam[4], bet[4];
#pragma unroll
  for (int kk = 0; kk < 4; ++kk) {
    gam[kk] = gamma[lcol + kk];
    bet[kk] = beta[lcol + kk];
  }

  float4 rst[4];
#pragma unroll
  for (int ps = 0; ps < 4; ++ps)
    rst[ps] = *(const float4*)(gr + hb + (size_t)(t0 + ps * 16 + ti) * Dx + lcol);
#pragma unroll
  for (int ps = 0; ps < 4; ++ps)
    *(float4*)(sR + (ps * 16 + ti) * LDP + lcol) = rst[ps];

  for (int tile = 0; tile < 4; ++tile) {
    __syncthreads();
    if (tile < 3) {  // T14: prefetch next r tile into registers during compute
      const int ts = t0 + (tile + 1) * 64;
#pragma unroll
      for (int ps = 0; ps < 4; ++ps)
        rst[ps] = *(const float4*)(gr + hb + (size_t)(ts + ps * 16 + ti) * Dx + lcol);
    }

    float acc[4][4];
#pragma unroll
    for (int tt = 0; tt < 4; ++tt)
#pragma unroll
      for (int kk = 0; kk < 4; ++kk) acc[tt][kk] = 0.f;

#pragma unroll
    for (int j4 = 0; j4 < 16; ++j4) {
      float rv[4][4], wv[4][4];
#pragma unroll
      for (int tt = 0; tt < 4; ++tt) {
        const float4 x = *(const float4*)(sR + (ti * 4 + tt) * LDP + j4 * 4);
        rv[tt][0] = x.x; rv[tt][1] = x.y; rv[tt][2] = x.z; rv[tt][3] = x.w;
      }
#pragma unroll
      for (int jj = 0; jj < 4; ++jj) {
        const float4 x = *(const float4*)(sW + (j4 * 4 + jj) * LDP + lcol);
        wv[jj][0] = x.x; wv[jj][1] = x.y; wv[jj][2] = x.z; wv[jj][3] = x.w;
      }
#pragma unroll
      for (int tt = 0; tt < 4; ++tt)
#pragma unroll
        for (int kk = 0; kk < 4; ++kk) {
          float a = acc[tt][kk];
          a = fmaf(rv[tt][0], wv[0][kk], a);
          a = fmaf(rv[tt][1], wv[1][kk], a);
          a = fmaf(rv[tt][2], wv[2][kk], a);
          a = fmaf(rv[tt][3], wv[3][kk], a);
          acc[tt][kk] = a;
        }
    }

    // epilogue: LN over dh (16 lanes x 4 local) + silu(g)
#pragma unroll
    for (int tt = 0; tt < 4; ++tt) {
      float s = acc[tt][0] + acc[tt][1] + acc[tt][2] + acc[tt][3];
      float sq = fmaf(acc[tt][0], acc[tt][0],
                 fmaf(acc[tt][1], acc[tt][1],
                 fmaf(acc[tt][2], acc[tt][2], acc[tt][3] * acc[tt][3])));
#pragma unroll
      for (int m = 1; m <= 8; m <<= 1) {
        s += __shfl_xor(s, m, 64);
        sq += __shfl_xor(sq, m, 64);
      }
      const float mu = s * 0.015625f;
      const float var = sq * 0.015625f - mu * mu;
      const float rstd = rsqrtf(var + 1e-5f);
      const int t = t0 + tile * 64 + ti * 4 + tt;
      const size_t go = hb + (size_t)t * Dx + lcol;
      const float4 g4 = *(const float4*)(gg + go);
      const float gxs[4] = {g4.x, g4.y, g4.z, g4.w};
      float ya[4];
#pragma unroll
      for (int kk = 0; kk < 4; ++kk) {
        const float y = (acc[tt][kk] - mu) * rstd * gam[kk] + bet[kk];
        const float gx = gxs[kk];
        const float sl = gx / (1.f + __expf(-gx));
        ya[kk] = y * sl;
      }
      *(float4*)(gout + go) = make_float4(ya[0], ya[1], ya[2], ya[3]);
    }

    if (tile < 3) {
      __syncthreads();
#pragma unroll
      for (int ps = 0; ps < 4; ++ps)
        *(float4*)(sR + (ps * 16 + ti) * LDP + lcol) = rst[ps];
    }
  }
}

extern "C" void kernel_launch(void* const* d_in, const int* in_sizes, int n_in,
                              void* d_out, int out_size, void* d_ws, size_t ws_size,
                              hipStream_t stream) {
  const float* r = (const float*)d_in[0];
  const float* w = (const float*)d_in[1];
  const float* k = (const float*)d_in[2];
  const float* v = (const float*)d_in[3];
  const float* g = (const float*)d_in[4];
  const float* u = (const float*)d_in[5];
  const float* gamma = (const float*)d_in[6];
  const float* beta = (const float*)d_in[7];
  float* out = (float*)d_out;

  // ws layout: partials 512*4096 f32 (8MB) | chunk prods 512*64 (128KB) | wkv 128*4096 (2MB)
  float* part = (float*)d_ws;
  float* prod = part + 512 * 4096;
  float* wkv = prod + 512 * 64;

  k_partial<<<512, 256, 0, stream>>>(w, k, v, part, prod);
  k_combine<<<128, 256, 0, stream>>>(part, prod, k, v, u, wkv);
  k_out<<<1024, 256, 0, stream>>>(r, g, wkv, gamma, beta, out);
}